// Round 1
// baseline (369.085 us; speedup 1.0000x reference)
//
#include <hip/hip_runtime.h>

// Problem constants (from reference setup_inputs): x (8,128,128,128) f32,
// kernel (4,4) f32, UP=2 -> out (8,128,256,256) f32.
#define NC   1024   // 8*128 fused
#define H    128
#define W    128
#define OH   256
#define OW   256

// 2x zero-insert upsample + 4-tap FIR, collapsed to direct gather:
// 1D: o even (i=o/2):  k[1]*x[i]   + k[3]*x[i-1]
//     o odd  (i=o/2):  k[0]*x[i+1] + k[2]*x[i]
// 2D = tensor product with full K[sy][sx] (handles non-separable K too).
__global__ __launch_bounds__(256) void upscale_kernel(
    const float* __restrict__ x,
    const float* __restrict__ K,
    float* __restrict__ out)
{
    int gid = blockIdx.x * blockDim.x + threadIdx.x;
    // layout: gid = ((nc * OH) + oy) * (OW/4) + ot
    int ot = gid & 63;            // OW/4 = 64 float4 groups per row
    int oy = (gid >> 6) & 255;    // wave-uniform (64 ot values per wave)
    int nc = gid >> 14;

    int iy = oy >> 1;
    int ay = oy & 1;
    int j0 = ot << 1;             // input col pair base; need cols j0-1..j0+2

    // row taps: ay=0 -> sy=1 @ iy, sy=3 @ iy-1 ; ay=1 -> sy=2 @ iy, sy=0 @ iy+1
    int r0  = iy;
    int r1  = ay ? iy + 1 : iy - 1;
    int sy0 = ay ? 2 : 1;
    int sy1 = ay ? 0 : 3;
    bool r1ok = (unsigned)r1 < (unsigned)H;

    const float* base = x + (size_t)nc * (H * W);

    // row r0, cols j0-1 .. j0+2 (zero at borders)
    float a0, a1, a2, a3;
    {
        const float* p = base + r0 * W + j0;
        a1 = p[0];
        a2 = p[1];
        a0 = (j0 > 0)     ? p[-1] : 0.f;
        a3 = (j0 + 2 < W) ? p[2]  : 0.f;
    }
    float b0 = 0.f, b1 = 0.f, b2 = 0.f, b3 = 0.f;
    if (r1ok) {
        const float* p = base + r1 * W + j0;
        b1 = p[0];
        b2 = p[1];
        b0 = (j0 > 0)     ? p[-1] : 0.f;
        b3 = (j0 + 2 < W) ? p[2]  : 0.f;
    }

    // wave-uniform kernel weights (sy0/sy1 uniform per wave)
    float k00 = K[sy0 * 4 + 0], k01 = K[sy0 * 4 + 1],
          k02 = K[sy0 * 4 + 2], k03 = K[sy0 * 4 + 3];
    float k10 = K[sy1 * 4 + 0], k11 = K[sy1 * 4 + 1],
          k12 = K[sy1 * 4 + 2], k13 = K[sy1 * 4 + 3];

    float4 o4;
    // col taps: ax=0 @ j: sx=1 col j,   sx=3 col j-1
    //           ax=1 @ j: sx=0 col j+1, sx=2 col j
    // ox = 4*ot + {0,1,2,3} -> (j,ax) = (j0,0),(j0,1),(j0+1,0),(j0+1,1)
    o4.x = k01 * a1 + k03 * a0 + k11 * b1 + k13 * b0;
    o4.y = k00 * a2 + k02 * a1 + k10 * b2 + k12 * b1;
    o4.z = k01 * a2 + k03 * a1 + k11 * b2 + k13 * b1;
    o4.w = k00 * a3 + k02 * a2 + k10 * b3 + k12 * b2;

    float4* po = (float4*)(out + (size_t)nc * (OH * OW) + (size_t)oy * OW + (ot << 2));
    *po = o4;
}

extern "C" void kernel_launch(void* const* d_in, const int* in_sizes, int n_in,
                              void* d_out, int out_size, void* d_ws, size_t ws_size,
                              hipStream_t stream) {
    const float* x   = (const float*)d_in[0];
    const float* K   = (const float*)d_in[1];
    float*       out = (float*)d_out;

    const int total_threads = NC * OH * (OW / 4);  // 16,777,216
    dim3 block(256);
    dim3 grid(total_threads / 256);                // 65,536 blocks
    upscale_kernel<<<grid, block, 0, stream>>>(x, K, out);
}

// Round 2
// 336.705 us; speedup vs baseline: 1.0962x; 1.0962x over previous
//
#include <hip/hip_runtime.h>

// x: (8,128,128,128) f32 -> out: (8,128,256,256) f32, 2x upsample + 4x4 FIR.
#define NC   1024   // 8*128 fused
#define H    128
#define W    128
#define OH   256
#define OW   256

// 1D collapse of zero-insert-2x + 4-tap FIR (verified round 0):
//   o even (i=o/2):  K[1]*x[i]   + K[3]*x[i-1]
//   o odd  (i=o/2):  K[0]*x[i+1] + K[2]*x[i]
// 2D: index structure separable; weights from full K[sy][sx].

// Accumulate one input row's contribution to 8 consecutive output cols.
// kr = K row (sy): .x=K[sy][0] .y=K[sy][1] .z=K[sy][2] .w=K[sy][3]
// Row data: L = col j0-1, v = cols j0..j0+3, R = col j0+4.
__device__ __forceinline__ void accum(float L, const float4& v, float R,
                                      const float4& kr, float o[8]) {
    float e1 = kr.y, e3 = kr.w;   // even out col: e1*x[j] + e3*x[j-1]
    float c0 = kr.x, c2 = kr.z;   // odd  out col: c0*x[j+1] + c2*x[j]
    o[0] += e1 * v.x + e3 * L;
    o[1] += c0 * v.y + c2 * v.x;
    o[2] += e1 * v.y + e3 * v.x;
    o[3] += c0 * v.z + c2 * v.y;
    o[4] += e1 * v.z + e3 * v.y;
    o[5] += c0 * v.w + c2 * v.z;
    o[6] += e1 * v.w + e3 * v.z;
    o[7] += c0 * R   + c2 * v.w;
}

__global__ __launch_bounds__(256) void upscale_kernel(
    const float* __restrict__ x,
    const float* __restrict__ Kp,
    float* __restrict__ out)
{
    int gid = blockIdx.x * blockDim.x + threadIdx.x;
    // gid = (nc*H + iy)*(W/4) + jg ; lanes: jg = lane&31, 2 adjacent iy per wave
    int jg = gid & 31;             // float4 column group, j0 = 4*jg
    int iy = (gid >> 5) & (H - 1); // input row
    int nc = gid >> 12;

    const float4* row = (const float4*)(x + (size_t)nc * (H * W));
    const float4 z = make_float4(0.f, 0.f, 0.f, 0.f);

    // 3 dense float4 loads: rows iy-1, iy, iy+1 (zero pad at image top/bottom)
    float4 vm = (iy > 0)     ? row[(size_t)(iy - 1) * (W / 4) + jg] : z;
    float4 v0 =                row[(size_t)iy       * (W / 4) + jg];
    float4 vp = (iy < H - 1) ? row[(size_t)(iy + 1) * (W / 4) + jg] : z;

    // Horizontal halo via 32-lane shuffles. W=128=32*4 so the 32-lane segment
    // boundary IS the image border, where the tap is zero — exact match.
    float Lm = __shfl_up(vm.w, 1, 32);
    float L0 = __shfl_up(v0.w, 1, 32);
    float Lp = __shfl_up(vp.w, 1, 32);
    float Rm = __shfl_down(vm.x, 1, 32);
    float R0 = __shfl_down(v0.x, 1, 32);
    float Rp = __shfl_down(vp.x, 1, 32);
    if (jg == 0)     { Lm = 0.f; L0 = 0.f; Lp = 0.f; }
    if (jg == W/4-1) { Rm = 0.f; R0 = 0.f; Rp = 0.f; }

    // Kernel rows (uniform-address float4 loads, L1 broadcast)
    const float4* K4 = (const float4*)Kp;
    float4 k0 = K4[0], k1 = K4[1], k2 = K4[2], k3 = K4[3];

    // even output row 2*iy:   sy=1 @ iy, sy=3 @ iy-1
    float oe[8] = {0.f, 0.f, 0.f, 0.f, 0.f, 0.f, 0.f, 0.f};
    accum(L0, v0, R0, k1, oe);
    accum(Lm, vm, Rm, k3, oe);
    // odd output row 2*iy+1:  sy=2 @ iy, sy=0 @ iy+1
    float oo[8] = {0.f, 0.f, 0.f, 0.f, 0.f, 0.f, 0.f, 0.f};
    accum(L0, v0, R0, k2, oo);
    accum(Lp, vp, Rp, k0, oo);

    float* ob = out + (size_t)nc * (OH * OW) + (size_t)(2 * iy) * OW + 8 * jg;
    ((float4*)ob)[0] = make_float4(oe[0], oe[1], oe[2], oe[3]);
    ((float4*)ob)[1] = make_float4(oe[4], oe[5], oe[6], oe[7]);
    float* ob2 = ob + OW;
    ((float4*)ob2)[0] = make_float4(oo[0], oo[1], oo[2], oo[3]);
    ((float4*)ob2)[1] = make_float4(oo[4], oo[5], oo[6], oo[7]);
}

extern "C" void kernel_launch(void* const* d_in, const int* in_sizes, int n_in,
                              void* d_out, int out_size, void* d_ws, size_t ws_size,
                              hipStream_t stream) {
    const float* x   = (const float*)d_in[0];
    const float* K   = (const float*)d_in[1];
    float*       out = (float*)d_out;

    const int total_threads = NC * H * (W / 4);   // 4,194,304
    dim3 block(256);
    dim3 grid(total_threads / 256);               // 16,384 blocks
    upscale_kernel<<<grid, block, 0, stream>>>(x, K, out);
}